// Round 7
// baseline (131.931 us; speedup 1.0000x reference)
//
#include <hip/hip_runtime.h>
#include <hip/hip_bf16.h>
#include <math.h>

#define HD 256
#define BB 64
#define DD 2048
#define NQ 4            // quarters per batch (512 rows each)
#define NST 8           // 64-row sub-tiles per quarter

typedef __attribute__((ext_vector_type(8))) short  short8;
typedef __attribute__((ext_vector_type(4))) float  float4v;
typedef __attribute__((ext_vector_type(4))) unsigned uint4v;
typedef __attribute__((ext_vector_type(4))) unsigned short ushort4v;

__device__ inline unsigned short f2bf(float f) {
    unsigned u = __builtin_bit_cast(unsigned, f);
    u += 0x7FFFu + ((u >> 16) & 1u);   // RNE
    return (unsigned short)(u >> 16);
}

__device__ inline unsigned cvt_pk_bf16(float lo, float hi) {
    unsigned r;
    asm("v_cvt_pk_bf16_f32 %0, %1, %2" : "=v"(r) : "v"(lo), "v"(hi));
    return r;
}
__device__ inline short8 cvt8(float4v lo, float4v hi) {
    uint4v u;
    u[0] = cvt_pk_bf16(lo[0], lo[1]);
    u[1] = cvt_pk_bf16(lo[2], lo[3]);
    u[2] = cvt_pk_bf16(hi[0], hi[1]);
    u[3] = cvt_pk_bf16(hi[2], hi[3]);
    return __builtin_bit_cast(short8, u);
}

__device__ inline float fast_exp2(float x) {
    float r;
    asm("v_exp_f32 %0, %1" : "=v"(r) : "v"(x));
    return r;
}
__device__ inline float fast_expf(float x) { return fast_exp2(x * 1.4426950408889634f); }
__device__ inline float fast_tanh(float x) {
    float y = x * 2.8853900817779268f;          // 2x * log2(e)
    y = fminf(fmaxf(y, -30.f), 30.f);
    float t = fast_exp2(y);
    float r;
    asm("v_rcp_f32 %0, %1" : "=v"(r) : "v"(t + 1.f));
    return (t - 1.f) * r;
}

#define SYNC_LDS() do { asm volatile("s_waitcnt lgkmcnt(0)" ::: "memory"); \
                        __builtin_amdgcn_s_barrier(); \
                        asm volatile("" ::: "memory"); } while (0)
#define WAITV8()  asm volatile("s_waitcnt vmcnt(8)" ::: "memory")
#define WAITV0()  asm volatile("s_waitcnt vmcnt(0)" ::: "memory")
#define BARRIER() do { __builtin_amdgcn_s_barrier(); asm volatile("" ::: "memory"); } while (0)

__device__ inline void load_lds16(const void* g, void* l) {
    __builtin_amdgcn_global_load_lds(
        (const __attribute__((address_space(1))) void*)g,
        (__attribute__((address_space(3))) void*)l, 16, 0, 0);
}

// stage one 64-row f32 sub-tile; wave stages rows [wave*8, wave*8+8).
// Source is pre-swizzled on 32B granules (g ^= r&7); LDS dest linear (rule 21).
__device__ inline void stage(const float* qtile, float* buf, int wave, int lane) {
    const int half = lane & 1;
    #pragma unroll
    for (int i = 0; i < 8; ++i) {
        int r = wave * 8 + i;
        int gsrc = ((((lane >> 1) ^ (r & 7)) << 1) | half) << 4;   // byte in row
        load_lds16((const char*)qtile + (size_t)r * 1024 + gsrc,
                   (char*)buf + r * 1024);
    }
}

// ---------------- kernel 0 (fused prep): W1 f32->bf16  AND  g23 ----------------
__global__ __launch_bounds__(256) void k_prep(const float* __restrict__ W1,
                                              unsigned short* __restrict__ w1b,
                                              const float* __restrict__ ctx,
                                              const float* __restrict__ hid,
                                              const float* __restrict__ W2,
                                              const float* __restrict__ b2,
                                              const float* __restrict__ W3,
                                              float* __restrict__ g23) {
    if (blockIdx.x < 64) {
        int i = blockIdx.x * 256 + threadIdx.x;
        float4v v = ((const float4v*)W1)[i];
        ushort4v o;
        o[0] = f2bf(v[0]); o[1] = f2bf(v[1]); o[2] = f2bf(v[2]); o[3] = f2bf(v[3]);
        ((ushort4v*)w1b)[i] = o;
    } else {
        int b = blockIdx.x - 64, t = threadIdx.x;
        __shared__ float c[HD], hh[HD];
        c[t]  = ctx[b * HD + t];
        hh[t] = hid[b * HD + t];
        __syncthreads();
        const float4v* w2 = (const float4v*)(W2 + (size_t)t * HD);
        const float4v* w3 = (const float4v*)(W3 + (size_t)t * HD);
        float acc = b2[t];
        #pragma unroll 8
        for (int k = 0; k < 64; ++k) {
            float4v a = w2[k], d = w3[k];
            int k4 = k * 4;
            acc += c[k4] * a[0] + c[k4 + 1] * a[1] + c[k4 + 2] * a[2] + c[k4 + 3] * a[3];
            acc += hh[k4] * d[0] + hh[k4 + 1] * d[1] + hh[k4 + 2] * d[2] + hh[k4 + 3] * d[3];
        }
        g23[b * HD + t] = acc;
    }
}

// ---------------- kernel 1: fused flash pipeline, 1 block/CU ----------------
// grid (4, 64), 512 thr (8 waves). Wave owns 32 h (W1 slice in 64 VGPR).
// Per 64-row sub-tile: gload_lds f32 (src-swizzled) -> MFMA C[h][d] -> tanh.W4
// partial scores -> redundant per-wave stats reduce -> PV (f32, per-wave cols).
__global__ __launch_bounds__(512, 2) void k_fused(const float* __restrict__ q,
                                                  const unsigned short* __restrict__ w1b,
                                                  const float* __restrict__ g23,
                                                  const float* __restrict__ W4,
                                                  float* __restrict__ pstats,
                                                  float* __restrict__ pO) {
    __shared__ __attribute__((aligned(16))) float buf0[64 * HD];   // 64 KB
    __shared__ __attribute__((aligned(16))) float buf1[64 * HD];   // 64 KB
    __shared__ float sp[8][64];

    const int t = threadIdx.x;
    const int qtr = blockIdx.x, b = blockIdx.y;
    const int lane = t & 63, wave = t >> 6;
    const int l15 = lane & 15, lk = lane >> 4;
    const int hb = wave * 32;
    const int cq = lane & 7, ro = lane >> 3;   // PV: col-quad, row-oct

    const float* qq = q + ((size_t)b * DD + qtr * 512) * HD;

    // issue sub-tile 0 immediately
    stage(qq, buf0, wave, lane);

    // W1 slice -> 64 VGPR (L2-hot after k_prep)
    short8 bfr[8][2];
    #pragma unroll
    for (int kb = 0; kb < 8; ++kb)
        #pragma unroll
        for (int nf = 0; nf < 2; ++nf)
            bfr[kb][nf] = *(const short8*)&w1b[(size_t)(hb + nf * 16 + l15) * HD + kb * 32 + lk * 8];

    // per-lane g23/W4 for C rows h = hb + nf*16 + lk*4 + r
    float gv[2][4], wv[2][4];
    #pragma unroll
    for (int nf = 0; nf < 2; ++nf)
        #pragma unroll
        for (int r = 0; r < 4; ++r) {
            int h = hb + nf * 16 + lk * 4 + r;
            gv[nf][r] = g23[b * HD + h];
            wv[nf][r] = W4[h];
        }

    float m = -1e30f, l = 0.f;
    float4v O = {0.f, 0.f, 0.f, 0.f};

    #pragma unroll
    for (int st = 0; st < NST; ++st) {
        float* cur = (st & 1) ? buf1 : buf0;
        float* nxt = (st & 1) ? buf0 : buf1;

        SYNC_LDS();                      // B1: all waves done with prev iteration (nxt free)
        if (st + 1 < NST) {
            stage(qq + (size_t)(st + 1) * 64 * HD, nxt, wave, lane);
            WAITV8();                    // drain THIS sub-tile's 8 loads; next 8 stay in flight
        } else {
            WAITV0();
        }
        BARRIER();                       // B2: cur fully staged by all waves

        // ---- passA: partial scores for all 64 rows x this wave's 32 h ----
        #pragma unroll
        for (int mf = 0; mf < 4; ++mf) {
            float4v acc0 = {0.f, 0.f, 0.f, 0.f}, acc1 = {0.f, 0.f, 0.f, 0.f};
            const int d = mf * 16 + l15;
            const int dsw = d & 7;
            #pragma unroll
            for (int kb = 0; kb < 8; ++kb) {
                int g = kb * 4 + lk;                       // 32B k-granule
                int byte = d * 1024 + ((g ^ dsw) << 5);
                float4v lo = *(const float4v*)((const char*)cur + byte);
                float4v hi = *(const float4v*)((const char*)cur + byte + 16);
                short8 bq = cvt8(lo, hi);
                acc0 = __builtin_amdgcn_mfma_f32_16x16x32_bf16(bfr[kb][0], bq, acc0, 0, 0, 0);
                acc1 = __builtin_amdgcn_mfma_f32_16x16x32_bf16(bfr[kb][1], bq, acc1, 0, 0, 0);
            }
            float s = 0.f;
            #pragma unroll
            for (int r = 0; r < 4; ++r) s += fast_tanh(acc0[r] + gv[0][r]) * wv[0][r];
            #pragma unroll
            for (int r = 0; r < 4; ++r) s += fast_tanh(acc1[r] + gv[1][r]) * wv[1][r];
            s += __shfl_xor(s, 16, 64);
            s += __shfl_xor(s, 32, 64);
            if (lk == 0) sp[wave][mf * 16 + l15] = s;
        }
        SYNC_LDS();                      // B3: sp published

        // ---- passB (redundant per wave): stats + online update + PV ----
        float sc = sp[0][lane] + sp[1][lane] + sp[2][lane] + sp[3][lane]
                 + sp[4][lane] + sp[5][lane] + sp[6][lane] + sp[7][lane];
        float tmax = sc;
        tmax = fmaxf(tmax, __shfl_xor(tmax, 1, 64));
        tmax = fmaxf(tmax, __shfl_xor(tmax, 2, 64));
        tmax = fmaxf(tmax, __shfl_xor(tmax, 4, 64));
        tmax = fmaxf(tmax, __shfl_xor(tmax, 8, 64));
        tmax = fmaxf(tmax, __shfl_xor(tmax, 16, 64));
        tmax = fmaxf(tmax, __shfl_xor(tmax, 32, 64));
        float mn  = fmaxf(m, tmax);
        float wexp = fast_expf(sc - mn);
        float tsum = wexp;
        tsum += __shfl_xor(tsum, 1, 64);
        tsum += __shfl_xor(tsum, 2, 64);
        tsum += __shfl_xor(tsum, 4, 64);
        tsum += __shfl_xor(tsum, 8, 64);
        tsum += __shfl_xor(tsum, 16, 64);
        tsum += __shfl_xor(tsum, 32, 64);
        float fct = fast_expf(m - mn);
        l = l * fct + tsum;
        m = mn;
        O *= fct;
        // PV: cols wave*32 + cq*4, rows d = ro*8 + i (f32 tile, swizzled granules)
        const int gq = wave * 4 + (cq >> 1);
        const int hoff = (cq & 1) << 4;
        #pragma unroll
        for (int i = 0; i < 8; ++i) {
            int d = ro * 8 + i;
            float wd = __shfl(wexp, d, 64);
            int byte = d * 1024 + (((gq ^ (d & 7))) << 5) + hoff;
            float4v v = *(const float4v*)((const char*)cur + byte);
            O += wd * v;
        }
    }

    // reduce O over the 8 row-octs (lanes sharing cq)
    #pragma unroll
    for (int j = 0; j < 4; ++j) {
        O[j] += __shfl_xor(O[j], 8, 64);
        O[j] += __shfl_xor(O[j], 16, 64);
        O[j] += __shfl_xor(O[j], 32, 64);
    }
    if (ro == 0)
        *(float4v*)&pO[((size_t)(b * NQ + qtr)) * HD + wave * 32 + cq * 4] = O;
    if (t == 0) {
        pstats[(b * NQ + qtr) * 2]     = m;
        pstats[(b * NQ + qtr) * 2 + 1] = l;
    }
}

// ---------------- kernel 2: combine 4 quarter-partials per batch ----------------
__global__ __launch_bounds__(256) void k_comb(const float* __restrict__ pstats,
                                              const float* __restrict__ pO,
                                              float* __restrict__ out) {
    int b = blockIdx.x, t = threadIdx.x;
    float M = -1e30f;
    #pragma unroll
    for (int c = 0; c < NQ; ++c) M = fmaxf(M, pstats[(b * NQ + c) * 2]);
    float L = 0.f, s = 0.f;
    #pragma unroll
    for (int c = 0; c < NQ; ++c) {
        float f = fast_expf(pstats[(b * NQ + c) * 2] - M);
        L += f * pstats[(b * NQ + c) * 2 + 1];
        s += f * pO[((size_t)(b * NQ + c)) * HD + t];
    }
    out[b * HD + t] = s / L;
}

extern "C" void kernel_launch(void* const* d_in, const int* in_sizes, int n_in,
                              void* d_out, int out_size, void* d_ws, size_t ws_size,
                              hipStream_t stream) {
    (void)in_sizes; (void)n_in; (void)out_size; (void)ws_size;
    const float* ctx = (const float*)d_in[0];
    const float* q   = (const float*)d_in[1];
    const float* hid = (const float*)d_in[2];
    const float* W1  = (const float*)d_in[3];
    const float* W2  = (const float*)d_in[4];
    const float* b2  = (const float*)d_in[5];
    const float* W3  = (const float*)d_in[6];
    const float* W4  = (const float*)d_in[7];
    // d_in[8] = b4: dropped (softmax shift-invariant)
    float* out = (float*)d_out;

    char* ws = (char*)d_ws;
    unsigned short* w1b = (unsigned short*)(ws);            // 131072 B
    float* g23    = (float*)(ws + 131072);                  //  65536 B
    float* pstats = (float*)(ws + 196608);                  //   4096 B
    float* pO     = (float*)(ws + 200704);                  // 262144 B

    k_prep <<<dim3(128), dim3(256), 0, stream>>>(W1, w1b, ctx, hid, W2, b2, W3, g23);
    k_fused<<<dim3(NQ, BB), dim3(512), 0, stream>>>(q, w1b, g23, W4, pstats, pO);
    k_comb <<<dim3(BB), dim3(256), 0, stream>>>(pstats, pO, out);
}

// Round 8
// 70.861 us; speedup vs baseline: 1.8618x; 1.8618x over previous
//
#include <hip/hip_runtime.h>
#include <hip/hip_bf16.h>
#include <math.h>

#define HD 256
#define BB 64
#define DD 2048
#define NQ 4            // quarters per batch (512 rows each)
#define NST 8           // 64-row sub-tiles per quarter

typedef __attribute__((ext_vector_type(8))) short  short8;
typedef __attribute__((ext_vector_type(4))) float  float4v;
typedef __attribute__((ext_vector_type(4))) unsigned uint4v;
typedef __attribute__((ext_vector_type(4))) unsigned short ushort4v;

__device__ inline unsigned short f2bf(float f) {
    unsigned u = __builtin_bit_cast(unsigned, f);
    u += 0x7FFFu + ((u >> 16) & 1u);   // RNE
    return (unsigned short)(u >> 16);
}

__device__ inline unsigned cvt_pk_bf16(float lo, float hi) {
    unsigned r;
    asm("v_cvt_pk_bf16_f32 %0, %1, %2" : "=v"(r) : "v"(lo), "v"(hi));
    return r;
}
__device__ inline short8 cvt8(float4v lo, float4v hi) {
    uint4v u;
    u[0] = cvt_pk_bf16(lo[0], lo[1]);
    u[1] = cvt_pk_bf16(lo[2], lo[3]);
    u[2] = cvt_pk_bf16(hi[0], hi[1]);
    u[3] = cvt_pk_bf16(hi[2], hi[3]);
    return __builtin_bit_cast(short8, u);
}

__device__ inline float fast_exp2(float x) {
    float r;
    asm("v_exp_f32 %0, %1" : "=v"(r) : "v"(x));
    return r;
}
__device__ inline float fast_expf(float x) { return fast_exp2(x * 1.4426950408889634f); }
__device__ inline float fast_tanh(float x) {
    float y = x * 2.8853900817779268f;          // 2x * log2(e)
    y = fminf(fmaxf(y, -30.f), 30.f);
    float t = fast_exp2(y);
    float r;
    asm("v_rcp_f32 %0, %1" : "=v"(r) : "v"(t + 1.f));
    return (t - 1.f) * r;
}

#define SYNC_LDS() do { asm volatile("s_waitcnt lgkmcnt(0)" ::: "memory"); \
                        __builtin_amdgcn_s_barrier(); \
                        asm volatile("" ::: "memory"); } while (0)
#define WAITV8()  asm volatile("s_waitcnt vmcnt(8)" ::: "memory")
#define WAITV0()  asm volatile("s_waitcnt vmcnt(0)" ::: "memory")
#define BARRIER() do { __builtin_amdgcn_s_barrier(); asm volatile("" ::: "memory"); } while (0)

__device__ inline void load_lds16(const void* g, void* l) {
    __builtin_amdgcn_global_load_lds(
        (const __attribute__((address_space(1))) void*)g,
        (__attribute__((address_space(3))) void*)l, 16, 0, 0);
}

// stage one 64-row f32 sub-tile; wave stages rows [wave*8, wave*8+8).
// Source is pre-swizzled on 32B granules (g ^= r&7); LDS dest linear (rule 21).
__device__ inline void stage(const float* qtile, float* buf, int wave, int lane) {
    const int half = lane & 1;
    #pragma unroll
    for (int i = 0; i < 8; ++i) {
        int r = wave * 8 + i;
        int gsrc = ((((lane >> 1) ^ (r & 7)) << 1) | half) << 4;   // byte in row
        load_lds16((const char*)qtile + (size_t)r * 1024 + gsrc,
                   (char*)buf + r * 1024);
    }
}

// ---------------- kernel 0 (fused prep): W1 f32->bf16  AND  g23 ----------------
__global__ __launch_bounds__(256) void k_prep(const float* __restrict__ W1,
                                              unsigned short* __restrict__ w1b,
                                              const float* __restrict__ ctx,
                                              const float* __restrict__ hid,
                                              const float* __restrict__ W2,
                                              const float* __restrict__ b2,
                                              const float* __restrict__ W3,
                                              float* __restrict__ g23) {
    if (blockIdx.x < 64) {
        int i = blockIdx.x * 256 + threadIdx.x;
        float4v v = ((const float4v*)W1)[i];
        ushort4v o;
        o[0] = f2bf(v[0]); o[1] = f2bf(v[1]); o[2] = f2bf(v[2]); o[3] = f2bf(v[3]);
        ((ushort4v*)w1b)[i] = o;
    } else {
        int b = blockIdx.x - 64, t = threadIdx.x;
        __shared__ float c[HD], hh[HD];
        c[t]  = ctx[b * HD + t];
        hh[t] = hid[b * HD + t];
        __syncthreads();
        const float4v* w2 = (const float4v*)(W2 + (size_t)t * HD);
        const float4v* w3 = (const float4v*)(W3 + (size_t)t * HD);
        float acc = b2[t];
        #pragma unroll 8
        for (int k = 0; k < 64; ++k) {
            float4v a = w2[k], d = w3[k];
            int k4 = k * 4;
            acc += c[k4] * a[0] + c[k4 + 1] * a[1] + c[k4 + 2] * a[2] + c[k4 + 3] * a[3];
            acc += hh[k4] * d[0] + hh[k4 + 1] * d[1] + hh[k4 + 2] * d[2] + hh[k4 + 3] * d[3];
        }
        g23[b * HD + t] = acc;
    }
}

// ---------------- kernel 1: fused flash pipeline, 1 block/CU ----------------
// grid (4, 64), 512 thr (8 waves). Wave owns 32 h (W1 slice in 64 VGPR).
// NOTE: no min-blocks clause — LDS (130KB) already forces 1 block/CU; capping
// VGPR at 128 caused the round-7 spill (WRITE_SIZE 146MB).
__global__ __launch_bounds__(512) void k_fused(const float* __restrict__ q,
                                               const unsigned short* __restrict__ w1b,
                                               const float* __restrict__ g23,
                                               const float* __restrict__ W4,
                                               float* __restrict__ pstats,
                                               float* __restrict__ pO) {
    __shared__ __attribute__((aligned(16))) float buf0[64 * HD];   // 64 KB
    __shared__ __attribute__((aligned(16))) float buf1[64 * HD];   // 64 KB
    __shared__ float sp[8][64];

    const int t = threadIdx.x;
    const int qtr = blockIdx.x, b = blockIdx.y;
    const int lane = t & 63, wave = t >> 6;
    const int l15 = lane & 15, lk = lane >> 4;
    const int hb = wave * 32;
    const int cq = lane & 7, ro = lane >> 3;   // PV: col-quad, row-oct

    const float* qq = q + ((size_t)b * DD + qtr * 512) * HD;

    // issue sub-tile 0 immediately
    stage(qq, buf0, wave, lane);

    // W1 slice -> 64 VGPR (L2-hot after k_prep)
    short8 bfr[8][2];
    #pragma unroll
    for (int kb = 0; kb < 8; ++kb)
        #pragma unroll
        for (int nf = 0; nf < 2; ++nf)
            bfr[kb][nf] = *(const short8*)&w1b[(size_t)(hb + nf * 16 + l15) * HD + kb * 32 + lk * 8];

    // per-lane g23/W4 for C rows h = hb + nf*16 + lk*4 + r
    float gv[2][4], wv[2][4];
    #pragma unroll
    for (int nf = 0; nf < 2; ++nf)
        #pragma unroll
        for (int r = 0; r < 4; ++r) {
            int h = hb + nf * 16 + lk * 4 + r;
            gv[nf][r] = g23[b * HD + h];
            wv[nf][r] = W4[h];
        }

    float m = -1e30f, l = 0.f;
    float4v O = {0.f, 0.f, 0.f, 0.f};
    float* cur = buf0;
    float* nxt = buf1;

    #pragma unroll 1
    for (int st = 0; st < NST; ++st) {
        SYNC_LDS();                      // B1: all waves done reading nxt (prev iter)
        if (st + 1 < NST) {
            stage(qq + (size_t)(st + 1) * 64 * HD, nxt, wave, lane);
            WAITV8();                    // drain cur's 8 loads; next 8 stay in flight
        } else {
            WAITV0();
        }
        BARRIER();                       // B2: cur fully staged by all waves

        // ---- passA: partial scores for all 64 rows x this wave's 32 h ----
        #pragma unroll
        for (int mf = 0; mf < 4; ++mf) {
            float4v acc0 = {0.f, 0.f, 0.f, 0.f}, acc1 = {0.f, 0.f, 0.f, 0.f};
            const int d = mf * 16 + l15;
            const int dsw = d & 7;
            #pragma unroll
            for (int kb = 0; kb < 8; ++kb) {
                int g = kb * 4 + lk;                       // 32B k-granule
                int byte = d * 1024 + ((g ^ dsw) << 5);
                float4v lo = *(const float4v*)((const char*)cur + byte);
                float4v hi = *(const float4v*)((const char*)cur + byte + 16);
                short8 bq = cvt8(lo, hi);
                acc0 = __builtin_amdgcn_mfma_f32_16x16x32_bf16(bfr[kb][0], bq, acc0, 0, 0, 0);
                acc1 = __builtin_amdgcn_mfma_f32_16x16x32_bf16(bfr[kb][1], bq, acc1, 0, 0, 0);
            }
            float s = 0.f;
            #pragma unroll
            for (int r = 0; r < 4; ++r) s += fast_tanh(acc0[r] + gv[0][r]) * wv[0][r];
            #pragma unroll
            for (int r = 0; r < 4; ++r) s += fast_tanh(acc1[r] + gv[1][r]) * wv[1][r];
            s += __shfl_xor(s, 16, 64);
            s += __shfl_xor(s, 32, 64);
            if (lk == 0) sp[wave][mf * 16 + l15] = s;
        }
        SYNC_LDS();                      // B3: sp published

        // ---- passB (redundant per wave): stats + online update + PV ----
        float sc = sp[0][lane] + sp[1][lane] + sp[2][lane] + sp[3][lane]
                 + sp[4][lane] + sp[5][lane] + sp[6][lane] + sp[7][lane];
        float tmax = sc;
        tmax = fmaxf(tmax, __shfl_xor(tmax, 1, 64));
        tmax = fmaxf(tmax, __shfl_xor(tmax, 2, 64));
        tmax = fmaxf(tmax, __shfl_xor(tmax, 4, 64));
        tmax = fmaxf(tmax, __shfl_xor(tmax, 8, 64));
        tmax = fmaxf(tmax, __shfl_xor(tmax, 16, 64));
        tmax = fmaxf(tmax, __shfl_xor(tmax, 32, 64));
        float mn  = fmaxf(m, tmax);
        float wexp = fast_expf(sc - mn);
        float tsum = wexp;
        tsum += __shfl_xor(tsum, 1, 64);
        tsum += __shfl_xor(tsum, 2, 64);
        tsum += __shfl_xor(tsum, 4, 64);
        tsum += __shfl_xor(tsum, 8, 64);
        tsum += __shfl_xor(tsum, 16, 64);
        tsum += __shfl_xor(tsum, 32, 64);
        float fct = fast_expf(m - mn);
        l = l * fct + tsum;
        m = mn;
        O *= fct;
        // PV: cols wave*32 + cq*4, rows d = ro*8 + i (f32 tile, swizzled granules)
        const int gq = wave * 4 + (cq >> 1);
        const int hoff = (cq & 1) << 4;
        #pragma unroll
        for (int i = 0; i < 8; ++i) {
            int d = ro * 8 + i;
            float wd = __shfl(wexp, d, 64);
            int byte = d * 1024 + (((gq ^ (d & 7))) << 5) + hoff;
            float4v v = *(const float4v*)((const char*)cur + byte);
            O += wd * v;
        }

        float* tmp = cur; cur = nxt; nxt = tmp;
    }

    // reduce O over the 8 row-octs (lanes sharing cq)
    #pragma unroll
    for (int j = 0; j < 4; ++j) {
        O[j] += __shfl_xor(O[j], 8, 64);
        O[j] += __shfl_xor(O[j], 16, 64);
        O[j] += __shfl_xor(O[j], 32, 64);
    }
    if (ro == 0)
        *(float4v*)&pO[((size_t)(b * NQ + qtr)) * HD + wave * 32 + cq * 4] = O;
    if (t == 0) {
        pstats[(b * NQ + qtr) * 2]     = m;
        pstats[(b * NQ + qtr) * 2 + 1] = l;
    }
}

// ---------------- kernel 2: combine 4 quarter-partials per batch ----------------
__global__ __launch_bounds__(256) void k_comb(const float* __restrict__ pstats,
                                              const float* __restrict__ pO,
                                              float* __restrict__ out) {
    int b = blockIdx.x, t = threadIdx.x;
    float M = -1e30f;
    #pragma unroll
    for (int c = 0; c < NQ; ++c) M = fmaxf(M, pstats[(b * NQ + c) * 2]);
    float L = 0.f, s = 0.f;
    #pragma unroll
    for (int c = 0; c < NQ; ++c) {
        float f = fast_expf(pstats[(b * NQ + c) * 2] - M);
        L += f * pstats[(b * NQ + c) * 2 + 1];
        s += f * pO[((size_t)(b * NQ + c)) * HD + t];
    }
    out[b * HD + t] = s / L;
}

extern "C" void kernel_launch(void* const* d_in, const int* in_sizes, int n_in,
                              void* d_out, int out_size, void* d_ws, size_t ws_size,
                              hipStream_t stream) {
    (void)in_sizes; (void)n_in; (void)out_size; (void)ws_size;
    const float* ctx = (const float*)d_in[0];
    const float* q   = (const float*)d_in[1];
    const float* hid = (const float*)d_in[2];
    const float* W1  = (const float*)d_in[3];
    const float* W2  = (const float*)d_in[4];
    const float* b2  = (const float*)d_in[5];
    const float* W3  = (const float*)d_in[6];
    const float* W4  = (const float*)d_in[7];
    // d_in[8] = b4: dropped (softmax shift-invariant)
    float* out = (float*)d_out;

    char* ws = (char*)d_ws;
    unsigned short* w1b = (unsigned short*)(ws);            // 131072 B
    float* g23    = (float*)(ws + 131072);                  //  65536 B
    float* pstats = (float*)(ws + 196608);                  //   4096 B
    float* pO     = (float*)(ws + 200704);                  // 262144 B

    k_prep <<<dim3(128), dim3(256), 0, stream>>>(W1, w1b, ctx, hid, W2, b2, W3, g23);
    k_fused<<<dim3(NQ, BB), dim3(512), 0, stream>>>(q, w1b, g23, W4, pstats, pO);
    k_comb <<<dim3(BB), dim3(256), 0, stream>>>(pstats, pO, out);
}